// Round 4
// baseline (238.499 us; speedup 1.0000x reference)
//
#include <hip/hip_runtime.h>
#include <hip/hip_bf16.h>

#define B_ 4
#define T_ 2048
#define C_ 1024
#define H_ 16
#define D_ 64
#define M_ (B_*T_)   // 8192

typedef __bf16 bf16x8 __attribute__((ext_vector_type(8)));
typedef float  f32x4  __attribute__((ext_vector_type(4)));
typedef float  f32x16 __attribute__((ext_vector_type(16)));

__device__ __forceinline__ unsigned short f2bf(float f) {
  unsigned u = __builtin_bit_cast(unsigned, f);
  u += 0x7FFF + ((u >> 16) & 1);   // round-to-nearest-even
  return (unsigned short)(u >> 16);
}

__device__ __forceinline__ void gload_lds16(const void* g, void* l) {
  __builtin_amdgcn_global_load_lds(
      (const __attribute__((address_space(1))) void*)g,
      (__attribute__((address_space(3))) void*)l, 16, 0, 0);
}

// ---------------- conversion: f32 -> bf16 (vectorized) ----------------
__global__ void cvt_f32_bf16(const float* __restrict__ in,
                             unsigned short* __restrict__ out, int n4) {
  int i = blockIdx.x * blockDim.x + threadIdx.x;
  if (i < n4) {
    float4 v = ((const float4*)in)[i];
    ushort4 o;
    o.x = f2bf(v.x); o.y = f2bf(v.y); o.z = f2bf(v.z); o.w = f2bf(v.w);
    ((ushort4*)out)[i] = o;
  }
}

// ------------- weight transpose + convert: W[K][N] f32 -> Wt[N][K] bf16 -------------
__global__ void transpose_cvt(const float* __restrict__ w0, const float* __restrict__ w1,
                              const float* __restrict__ w2, const float* __restrict__ w3,
                              unsigned short* __restrict__ t0, unsigned short* __restrict__ t1,
                              unsigned short* __restrict__ t2, unsigned short* __restrict__ t3) {
  __shared__ float tile[32][33];
  const float* src; unsigned short* dst;
  switch (blockIdx.z) {
    case 0: src = w0; dst = t0; break;
    case 1: src = w1; dst = t1; break;
    case 2: src = w2; dst = t2; break;
    default: src = w3; dst = t3; break;
  }
  int bx = blockIdx.x * 32;  // n base
  int by = blockIdx.y * 32;  // k base
  int tx = threadIdx.x, ty = threadIdx.y;
  #pragma unroll
  for (int j = 0; j < 4; ++j)
    tile[ty + 8*j][tx] = src[(size_t)(by + ty + 8*j) * C_ + bx + tx];
  __syncthreads();
  #pragma unroll
  for (int j = 0; j < 4; ++j)
    dst[(size_t)(bx + ty + 8*j) * C_ + by + tx] = f2bf(tile[tx][ty + 8*j]);
}

// ---------------- bf16 MFMA GEMM: A[M][K] * Bt[N][K]^T + bias, then *oscale ----------------
// MODE 0: store bf16, head-split [B][H][T][D]
// MODE 1: store bf16, head-split transposed [B][H][D][T] with key-permuted order
//         (t bits 2<->3 swapped within each 16-group) for direct PV A-fragment reads
// MODE 2: store f32 [M][N]                                 (final output)
template<int MODE>
__global__ __launch_bounds__(256, 2)
void gemm_bf16(const unsigned short* __restrict__ A,
               const unsigned short* __restrict__ Bt,
               const float* __restrict__ bias,
               void* __restrict__ Cout, int K, int N, float oscale)
{
  __shared__ unsigned short lsA[128 * 64];
  __shared__ unsigned short lsB[128 * 64];
  const int wave = threadIdx.x >> 6;
  const int lane = threadIdx.x & 63;
  const int rowBase = blockIdx.y * 128;
  const int colBase = blockIdx.x * 128;
  const int rowOff = (wave >> 1) * 64;
  const int colOff = (wave & 1) * 64;
  const int lr = lane & 15;
  const int lg = lane >> 4;

  f32x4 acc[4][4] = {};

  const int chunkRow = lane >> 3;
  const int srcColE  = (((lane & 7) ^ (lane >> 3)) * 8);

  for (int k0 = 0; k0 < K; k0 += 64) {
    #pragma unroll
    for (int c = 0; c < 4; ++c) {
      int chunk = c * 4 + wave;
      int r = chunk * 8 + chunkRow;
      gload_lds16(A  + (size_t)(rowBase + r) * K + k0 + srcColE, &lsA[chunk * 512]);
      gload_lds16(Bt + (size_t)(colBase + r) * K + k0 + srcColE, &lsB[chunk * 512]);
    }
    __syncthreads();
    #pragma unroll
    for (int kk = 0; kk < 2; ++kk) {
      bf16x8 af[4], bfr[4];
      const int kbyte = (kk * 32 + lg * 8) * 2;
      #pragma unroll
      for (int m = 0; m < 4; ++m) {
        int row = rowOff + m * 16 + lr;
        af[m] = *(const bf16x8*)((const char*)lsA + row * 128 + (kbyte ^ ((row & 7) << 4)));
      }
      #pragma unroll
      for (int n = 0; n < 4; ++n) {
        int row = colOff + n * 16 + lr;
        bfr[n] = *(const bf16x8*)((const char*)lsB + row * 128 + (kbyte ^ ((row & 7) << 4)));
      }
      #pragma unroll
      for (int m = 0; m < 4; ++m)
        #pragma unroll
        for (int n = 0; n < 4; ++n)
          acc[m][n] = __builtin_amdgcn_mfma_f32_16x16x32_bf16(af[m], bfr[n], acc[m][n], 0, 0, 0);
    }
    __syncthreads();
  }

  #pragma unroll
  for (int m = 0; m < 4; ++m) {
    int row0 = rowBase + rowOff + m * 16 + lg * 4;
    #pragma unroll
    for (int n = 0; n < 4; ++n) {
      int col = colBase + colOff + n * 16 + lr;
      float bs = bias[col];
      if (MODE == 1) {
        int b = row0 >> 11, t = row0 & 2047;
        int t2 = (t & ~12) | ((t & 4) << 1) | ((t & 8) >> 1);  // key-perm (bits 2<->3)
        int h = col >> 6, d = col & 63;
        ushort4 o;
        o.x = f2bf((acc[m][n][0] + bs) * oscale);
        o.y = f2bf((acc[m][n][1] + bs) * oscale);
        o.z = f2bf((acc[m][n][2] + bs) * oscale);
        o.w = f2bf((acc[m][n][3] + bs) * oscale);
        *(ushort4*)((unsigned short*)Cout + (((size_t)b * H_ + h) * D_ + d) * T_ + t2) = o;
      } else {
        #pragma unroll
        for (int j = 0; j < 4; ++j) {
          float v = (acc[m][n][j] + bs) * oscale;
          int r = row0 + j;
          if (MODE == 2) {
            ((float*)Cout)[(size_t)r * N + col] = v;
          } else {
            int b = r >> 11, t = r & 2047;
            int h = col >> 6, d = col & 63;
            ((unsigned short*)Cout)[((((size_t)b * H_ + h) * T_ + t) << 6) + d] = f2bf(v);
          }
        }
      }
    }
  }
}

// ---------------- causal flash attention, 4 waves x 32 q-rows, LDS-staged K/V ----------------
// q,k: [B][H][T][D] bf16 (q pre-scaled by log2e/sqrt(D)) ; vp: [B][H][D][T] bf16 key-permuted ;
// y: [B][T][C] bf16. Swapped QK^T (S^T = K Q^T) and swapped PV (O^T = Vp P^T) keep softmax
// fully lane-local; P^T B-fragments come straight from S^T accumulator registers.
__global__ __launch_bounds__(256, 4)
void attn4(const unsigned short* __restrict__ q,
           const unsigned short* __restrict__ k,
           const unsigned short* __restrict__ vp,
           unsigned short* __restrict__ y)
{
  __shared__ unsigned short lsK[2][64 * 64];
  __shared__ unsigned short lsV[2][64 * 64];
  const int tid  = threadIdx.x;
  const int wave = tid >> 6;
  const int lane = tid & 63;
  const int col  = lane & 31;   // query (or K/V row) index within 32
  const int hi   = lane >> 5;
  const int bh = blockIdx.y;
  const int b = bh >> 4, h = bh & 15;
  const int qt = gridDim.x - 1 - blockIdx.x;   // longest-first
  const int q0 = qt * 128 + wave * 32;
  const unsigned short* qh = q  + (size_t)bh * T_ * D_;
  const unsigned short* kh = k  + (size_t)bh * T_ * D_;
  const unsigned short* vh = vp + (size_t)bh * D_ * T_;

  // staging source (inverse-swizzled): thread t stages LDS chunks t and t+256
  const int srow = tid >> 3;                                // 0..31
  const int srcE = ((tid & 7) * 8) ^ ((srow & 7) << 3);
  const unsigned short* ksrc = kh + srow * D_ + srcE;       // rows srow / srow+32
  const unsigned short* vsrc = vh + srow * T_ + srcE;

  // Q B-fragments: bqf[ks] supplies Q[q0+col][ks*16 + hi*8 + e]
  bf16x8 bqf[4];
  {
    const unsigned short* qrow = qh + (size_t)(q0 + col) * D_ + hi * 8;
    #pragma unroll
    for (int ks = 0; ks < 4; ++ks) bqf[ks] = *(const bf16x8*)(qrow + ks * 16);
  }

  f32x16 ot0 = {}, ot1 = {};
  float m = -INFINITY, l = 0.f;
  const int swz = (col & 7) << 4;
  const int nsteps = (qt + 1) * 2;

  // prologue: stage tile 0
  gload_lds16(ksrc,           &lsK[0][tid * 8]);
  gload_lds16(ksrc + 32 * D_, &lsK[0][(tid + 256) * 8]);
  gload_lds16(vsrc,           &lsV[0][tid * 8]);
  gload_lds16(vsrc + 32 * T_, &lsV[0][(tid + 256) * 8]);
  __syncthreads();

  for (int s = 0; s < nsteps; ++s) {
    const int n0 = s * 64;
    const unsigned short* baseK = (s & 1) ? lsK[1] : lsK[0];
    const unsigned short* baseV = (s & 1) ? lsV[1] : lsV[0];
    if (s + 1 < nsteps) {
      unsigned short* nK = (s & 1) ? lsK[0] : lsK[1];
      unsigned short* nV = (s & 1) ? lsV[0] : lsV[1];
      const unsigned short* kg = ksrc + (size_t)(s + 1) * 64 * D_;
      const unsigned short* vg = vsrc + (s + 1) * 64;
      gload_lds16(kg,           nK + tid * 8);
      gload_lds16(kg + 32 * D_, nK + (tid + 256) * 8);
      gload_lds16(vg,           nV + tid * 8);
      gload_lds16(vg + 32 * T_, nV + (tid + 256) * 8);
    }
    if (n0 <= q0 + 31) {
      const bool two = (n0 < q0);   // upper 32 keys live?
      // ---- QK^T ----
      f32x16 st0 = {};
      f32x16 st1;
      {
        const char* kb0 = (const char*)baseK + col * 128;
        __builtin_amdgcn_s_setprio(1);
        #pragma unroll
        for (int ks = 0; ks < 4; ++ks) {
          bf16x8 ak = *(const bf16x8*)(kb0 + ((ks * 32 + hi * 16) ^ swz));
          st0 = __builtin_amdgcn_mfma_f32_32x32x16_bf16(ak, bqf[ks], st0, 0, 0, 0);
        }
        __builtin_amdgcn_s_setprio(0);
        if (two) {
          f32x16 a = {};
          const char* kb1 = kb0 + 32 * 128;
          __builtin_amdgcn_s_setprio(1);
          #pragma unroll
          for (int ks = 0; ks < 4; ++ks) {
            bf16x8 ak = *(const bf16x8*)(kb1 + ((ks * 32 + hi * 16) ^ swz));
            a = __builtin_amdgcn_mfma_f32_32x32x16_bf16(ak, bqf[ks], a, 0, 0, 0);
          }
          __builtin_amdgcn_s_setprio(0);
          st1 = a;
        }
      }
      // ---- causal mask (diagonal tiles only) ----
      if (n0 + 63 > q0) {
        #pragma unroll
        for (int r = 0; r < 16; ++r) {
          int key0 = n0 + (r & 3) + 8 * (r >> 2) + 4 * hi;
          if (key0 > q0 + col) st0[r] = -INFINITY;
          if (two) { if (key0 + 32 > q0 + col) st1[r] = -INFINITY; }
        }
      }
      // ---- online softmax (lane-local, exp2 domain, defer-max THR=8) ----
      float mm;
      {
        float t0_ = fmaxf(fmaxf(st0[0], st0[1]), st0[2]);
        float t1_ = fmaxf(fmaxf(st0[3], st0[4]), st0[5]);
        float t2_ = fmaxf(fmaxf(st0[6], st0[7]), st0[8]);
        float t3_ = fmaxf(fmaxf(st0[9], st0[10]), st0[11]);
        float t4_ = fmaxf(fmaxf(st0[12], st0[13]), st0[14]);
        float t5_ = st0[15];
        if (two) {
          t0_ = fmaxf(t0_, fmaxf(fmaxf(st1[0], st1[1]), st1[2]));
          t1_ = fmaxf(t1_, fmaxf(fmaxf(st1[3], st1[4]), st1[5]));
          t2_ = fmaxf(t2_, fmaxf(fmaxf(st1[6], st1[7]), st1[8]));
          t3_ = fmaxf(t3_, fmaxf(fmaxf(st1[9], st1[10]), st1[11]));
          t4_ = fmaxf(t4_, fmaxf(fmaxf(st1[12], st1[13]), st1[14]));
          t5_ = fmaxf(t5_, st1[15]);
        }
        mm = fmaxf(fmaxf(fmaxf(t0_, t1_), t2_), fmaxf(fmaxf(t3_, t4_), t5_));
      }
      mm = fmaxf(mm, __shfl_xor(mm, 32));
      if (!__all(mm <= m + 8.f)) {
        float mnew = fmaxf(m, mm);
        float corr = exp2f(m - mnew);
        m = mnew;
        l *= corr;
        #pragma unroll
        for (int r = 0; r < 16; ++r) { ot0[r] *= corr; ot1[r] *= corr; }
      }
      bf16x8 pf[4];
      float psum = 0.f;
      #pragma unroll
      for (int half = 0; half < 2; ++half) {
        bf16x8 w;
        #pragma unroll
        for (int e = 0; e < 8; ++e) {
          float pv = exp2f(st0[half * 8 + e] - m);
          psum += pv;
          w[e] = (__bf16)pv;
        }
        pf[half] = w;
      }
      if (two) {
        #pragma unroll
        for (int half = 0; half < 2; ++half) {
          bf16x8 w;
          #pragma unroll
          for (int e = 0; e < 8; ++e) {
            float pv = exp2f(st1[half * 8 + e] - m);
            psum += pv;
            w[e] = (__bf16)pv;
          }
          pf[2 + half] = w;
        }
      }
      psum += __shfl_xor(psum, 32);
      l += psum;
      // ---- PV: O^T += Vp · P^T ----
      {
        const char* vb0 = (const char*)baseV + col * 128;
        const char* vb1 = vb0 + 32 * 128;
        __builtin_amdgcn_s_setprio(1);
        #pragma unroll
        for (int ks = 0; ks < 2; ++ks) {
          bf16x8 av0 = *(const bf16x8*)(vb0 + ((ks * 32 + hi * 16) ^ swz));
          bf16x8 av1 = *(const bf16x8*)(vb1 + ((ks * 32 + hi * 16) ^ swz));
          ot0 = __builtin_amdgcn_mfma_f32_32x32x16_bf16(av0, pf[ks], ot0, 0, 0, 0);
          ot1 = __builtin_amdgcn_mfma_f32_32x32x16_bf16(av1, pf[ks], ot1, 0, 0, 0);
        }
        if (two) {
          #pragma unroll
          for (int ks = 2; ks < 4; ++ks) {
            bf16x8 av0 = *(const bf16x8*)(vb0 + ((ks * 32 + hi * 16) ^ swz));
            bf16x8 av1 = *(const bf16x8*)(vb1 + ((ks * 32 + hi * 16) ^ swz));
            ot0 = __builtin_amdgcn_mfma_f32_32x32x16_bf16(av0, pf[ks], ot0, 0, 0, 0);
            ot1 = __builtin_amdgcn_mfma_f32_32x32x16_bf16(av1, pf[ks], ot1, 0, 0, 0);
          }
        }
        __builtin_amdgcn_s_setprio(0);
      }
    }
    __syncthreads();
  }

  // ---- normalize + store y[B][T][C] ----
  float inv = 1.f / l;
  unsigned short* yrow = y + ((size_t)b * T_ + q0 + col) * C_ + h * D_;
  #pragma unroll
  for (int a = 0; a < 4; ++a) {
    ushort4 o4;
    o4.x = f2bf(ot0[4 * a + 0] * inv);
    o4.y = f2bf(ot0[4 * a + 1] * inv);
    o4.z = f2bf(ot0[4 * a + 2] * inv);
    o4.w = f2bf(ot0[4 * a + 3] * inv);
    *(ushort4*)(yrow + 8 * a + 4 * hi) = o4;
  }
  #pragma unroll
  for (int a = 0; a < 4; ++a) {
    ushort4 o4;
    o4.x = f2bf(ot1[4 * a + 0] * inv);
    o4.y = f2bf(ot1[4 * a + 1] * inv);
    o4.z = f2bf(ot1[4 * a + 2] * inv);
    o4.w = f2bf(ot1[4 * a + 3] * inv);
    *(ushort4*)(yrow + 32 + 8 * a + 4 * hi) = o4;
  }
}

extern "C" void kernel_launch(void* const* d_in, const int* in_sizes, int n_in,
                              void* d_out, int out_size, void* d_ws, size_t ws_size,
                              hipStream_t stream) {
  const float* x  = (const float*)d_in[0];
  const float* Wq = (const float*)d_in[1];
  const float* bq = (const float*)d_in[2];
  const float* Wk = (const float*)d_in[3];
  const float* bk = (const float*)d_in[4];
  const float* Wv = (const float*)d_in[5];
  const float* bv = (const float*)d_in[6];
  const float* Wp = (const float*)d_in[7];
  const float* bp = (const float*)d_in[8];
  float* out = (float*)d_out;

  char* ws = (char*)d_ws;
  unsigned short* xb  = (unsigned short*)ws; ws += (size_t)M_ * C_ * 2;
  unsigned short* wqt = (unsigned short*)ws; ws += (size_t)C_ * C_ * 2;
  unsigned short* wkt = (unsigned short*)ws; ws += (size_t)C_ * C_ * 2;
  unsigned short* wvt = (unsigned short*)ws; ws += (size_t)C_ * C_ * 2;
  unsigned short* wpt = (unsigned short*)ws; ws += (size_t)C_ * C_ * 2;
  unsigned short* qb  = (unsigned short*)ws; ws += (size_t)M_ * C_ * 2;
  unsigned short* kb  = (unsigned short*)ws; ws += (size_t)M_ * C_ * 2;
  unsigned short* vtb = (unsigned short*)ws; ws += (size_t)M_ * C_ * 2;
  unsigned short* yb  = (unsigned short*)ws; ws += (size_t)M_ * C_ * 2;

  cvt_f32_bf16<<<dim3((M_ * C_ / 4 + 255) / 256), dim3(256), 0, stream>>>(x, xb, M_ * C_ / 4);
  transpose_cvt<<<dim3(32, 32, 4), dim3(32, 8), 0, stream>>>(Wq, Wk, Wv, Wp, wqt, wkt, wvt, wpt);

  dim3 ggrid(C_ / 128, M_ / 128);
  const float qscale = 0.125f * 1.4426950408889634f;  // 1/sqrt(64) * log2(e): exp2-domain softmax
  gemm_bf16<0><<<ggrid, dim3(256), 0, stream>>>(xb, wqt, bq, qb, C_, C_, qscale);
  gemm_bf16<0><<<ggrid, dim3(256), 0, stream>>>(xb, wkt, bk, kb, C_, C_, 1.f);
  gemm_bf16<1><<<ggrid, dim3(256), 0, stream>>>(xb, wvt, bv, vtb, C_, C_, 1.f);

  attn4<<<dim3(T_ / 128, B_ * H_), dim3(256), 0, stream>>>(qb, kb, vtb, yb);

  gemm_bf16<2><<<ggrid, dim3(256), 0, stream>>>(yb, wpt, bp, out, C_, C_, 1.f);
}